// Round 3
// baseline (767.724 us; speedup 1.0000x reference)
//
#include <hip/hip_runtime.h>
#include <hip/hip_bf16.h>
#include <math.h>

#define E_EXPERTS 8
#define D_DIM 768
#define H_DIM 3072
#define N_TOK 8192          // B*T = 4*2048
#define SLOTS (2 * N_TOK)

typedef unsigned short ushort_t;
typedef __attribute__((ext_vector_type(8))) __bf16 bf16x8;
typedef __attribute__((ext_vector_type(4))) float f32x4;

__device__ __forceinline__ unsigned short f2bf(float f) {
    unsigned int u = __float_as_uint(f);
    unsigned int r = (u + 0x7FFFu + ((u >> 16) & 1u)) >> 16;
    return (unsigned short)r;
}

// async 16B global -> LDS (wave-uniform LDS base + lane*16; global addr per-lane)
__device__ __forceinline__ void gload_lds16(const void* g, void* l) {
    __builtin_amdgcn_global_load_lds(
        (const __attribute__((address_space(1))) unsigned int*)g,
        (__attribute__((address_space(3))) unsigned int*)l, 16, 0, 0);
}

// ---------------- prep kernels ----------------

// dst[e][c][r] = bf16(src[e][r][c]);  R,C multiples of 64
__global__ void transpose_conv_kernel(const float* __restrict__ src, ushort_t* __restrict__ dst,
                                      int R, int C) {
    __shared__ float tile[64][65];
    int e = blockIdx.z;
    const float* S = src + (size_t)e * R * C;
    ushort_t* Dp = dst + (size_t)e * R * C;
    int c0 = blockIdx.x * 64, r0 = blockIdx.y * 64;
    int tx = threadIdx.x & 15, ty = threadIdx.x >> 4;  // 16 x 16
#pragma unroll
    for (int p = 0; p < 4; p++) {
        float4 v = *(const float4*)&S[(size_t)(r0 + ty + 16 * p) * C + c0 + tx * 4];
        tile[ty + 16 * p][tx * 4 + 0] = v.x;
        tile[ty + 16 * p][tx * 4 + 1] = v.y;
        tile[ty + 16 * p][tx * 4 + 2] = v.z;
        tile[ty + 16 * p][tx * 4 + 3] = v.w;
    }
    __syncthreads();
#pragma unroll
    for (int p = 0; p < 4; p++) {
        int cc = ty + 16 * p;
        int rr = tx * 4;
        ushort4 o;
        o.x = f2bf(tile[rr + 0][cc]);
        o.y = f2bf(tile[rr + 1][cc]);
        o.z = f2bf(tile[rr + 2][cc]);
        o.w = f2bf(tile[rr + 3][cc]);
        *(ushort4*)&Dp[(size_t)(c0 + cc) * R + r0 + rr] = o;
    }
}

// ---------------- routing (fused with x -> bf16 conversion) ----------------

__global__ void gate_kernel(const float* __restrict__ x, const float* __restrict__ Wg,
                            const float* __restrict__ bg, ushort_t* __restrict__ xb,
                            int* __restrict__ top_idx, float* __restrict__ top_w,
                            int* __restrict__ counts) {
    int w = threadIdx.x >> 6, lane = threadIdx.x & 63;
    int t = blockIdx.x * 4 + w;
    if (t >= N_TOK) return;
    const float* xr = x + (size_t)t * D_DIM;
    float xs[12];
#pragma unroll
    for (int j = 0; j < 12; j++) xs[j] = xr[lane + 64 * j];
#pragma unroll
    for (int j = 0; j < 12; j++) xb[(size_t)t * D_DIM + lane + 64 * j] = f2bf(xs[j]);
    float pr[8];
#pragma unroll
    for (int ee = 0; ee < 8; ee++) {
        const float* wr = Wg + ee * D_DIM;
        float p = 0.f;
#pragma unroll
        for (int j = 0; j < 12; j++) p += xs[j] * wr[lane + 64 * j];
#pragma unroll
        for (int o = 32; o > 0; o >>= 1) p += __shfl_xor(p, o);
        pr[ee] = p + bg[ee];
    }
    float mx = pr[0];
#pragma unroll
    for (int ee = 1; ee < 8; ee++) mx = fmaxf(mx, pr[ee]);
    float s = 0.f;
#pragma unroll
    for (int ee = 0; ee < 8; ee++) { pr[ee] = expf(pr[ee] - mx); s += pr[ee]; }
    float inv = 1.f / s;
#pragma unroll
    for (int ee = 0; ee < 8; ee++) pr[ee] *= inv;
    int i0 = 0;
#pragma unroll
    for (int ee = 1; ee < 8; ee++) if (pr[ee] > pr[i0]) i0 = ee;
    int i1 = -1;
#pragma unroll
    for (int ee = 0; ee < 8; ee++) {
        if (ee == i0) continue;
        if (i1 < 0 || pr[ee] > pr[i1]) i1 = ee;
    }
    if (lane == 0) {
        top_idx[2 * t] = i0;
        top_idx[2 * t + 1] = i1;
        top_w[2 * t] = pr[i0];
        top_w[2 * t + 1] = pr[i1];
        atomicAdd(&counts[i0], 1);
        atomicAdd(&counts[i1], 1);
    }
}

__global__ void scan_kernel(const int* __restrict__ counts, int* __restrict__ offsets,
                            int* __restrict__ cursors) {
    if (threadIdx.x == 0) {
        int acc = 0;
        for (int e = 0; e < E_EXPERTS; e++) { offsets[e] = acc; acc += counts[e]; }
    }
    if (threadIdx.x < E_EXPERTS) cursors[threadIdx.x] = 0;
}

__global__ void scatter_kernel(const int* __restrict__ top_idx, const float* __restrict__ top_w,
                               const int* __restrict__ offsets, int* __restrict__ cursors,
                               int* __restrict__ perm, float* __restrict__ wgt) {
    int t = blockIdx.x * blockDim.x + threadIdx.x;
    if (t >= N_TOK) return;
#pragma unroll
    for (int sl = 0; sl < 2; sl++) {
        int ee = top_idx[2 * t + sl];
        int p = atomicAdd(&cursors[ee], 1);
        int s = offsets[ee] + p;
        perm[s] = t;
        wgt[s] = top_w[2 * t + sl];
    }
}

// ---------------- expert GEMMs: 256x256 8-phase schedule (T3+T4+T5, linear LDS) ----------------
// 512 threads = 8 waves (2M x 4N). BM=BN=256, BK=64. LDS: 2 dbuf x 256 x 64 x bf16 for A and B.
// Per tile t (4 phases): p0 reads all B frags + A rows 0-1, p1/p2/p3 read A rows 2-3/4-5/6-7.
// Staging: p0/p1 -> A_{t+1} h0/h1 (into slot t+1&1, freed at t start); p2/p3 -> B_{t+2} h0/h1
// (slot t&1 B, consumed entirely at tile t's p0). Boundary wait vmcnt(4) (2 half-tiles in flight).
// MODE 0: A gathered via perm, B = W1T[e], epilogue GELU -> Hout bf16
// MODE 1: A = Hb contiguous,  B = W2T[e], epilogue weighted atomic -> Out f32
template <int MODE>
__global__ __launch_bounds__(512, 2) void moe_gemm_kernel(
    const ushort_t* __restrict__ A, const ushort_t* __restrict__ BT,
    const float* __restrict__ bias, const int* __restrict__ offsets,
    const int* __restrict__ counts, const int* __restrict__ perm,
    const float* __restrict__ wgt, ushort_t* __restrict__ Hout, float* __restrict__ Out) {
    constexpr int K = (MODE == 0) ? D_DIM : H_DIM;
    constexpr int N = (MODE == 0) ? H_DIM : D_DIM;
    constexpr int KT = K / 64;

    const int e = blockIdx.z;
    const int ne = counts[e];
    const int m0 = blockIdx.y * 256;
    if (m0 >= ne) return;
    const int n0 = blockIdx.x * 256;
    const int base = offsets[e];
    const ushort_t* Bt = BT + (size_t)e * ((size_t)N * K);

    __shared__ alignas(16) ushort_t As[2 * 256 * 64];
    __shared__ alignas(16) ushort_t Bs[2 * 256 * 64];

    const int tid = threadIdx.x;
    const int lane = tid & 63;
    const int w = tid >> 6;
    const int wm = w >> 2, wn = w & 3;           // 2 x 4 wave grid
    const int lr = lane & 15, lk = (lane >> 4) * 8;

    // staging geometry: seg = tid + i*512; row = seg>>3 (0..127), col8 = (seg&7)*8
    const int r0s = tid >> 3;                    // 0..63 ; +64 for i=1
    const int c8 = (tid & 7) * 8;
    int aoff[2][2], boff[2][2];                  // [half][i], 32-bit element offsets
#pragma unroll
    for (int H = 0; H < 2; H++)
#pragma unroll
        for (int i = 0; i < 2; i++) {
            int trow = H * 128 + r0s + i * 64;
            int rcl = min(m0 + trow, ne - 1);
            int arow = (MODE == 0) ? perm[base + rcl] : (base + rcl);
            aoff[H][i] = arow * K + c8;
            boff[H][i] = (n0 + trow) * K + c8;
        }

    auto stageA = [&](int tt, int H) {
#pragma unroll
        for (int i = 0; i < 2; i++)
            gload_lds16(A + (size_t)aoff[H][i] + (size_t)tt * 64,
                        &As[(tt & 1) * 16384 + H * 8192 + (w * 64 + i * 512) * 8]);
    };
    auto stageB = [&](int tt, int H) {
#pragma unroll
        for (int i = 0; i < 2; i++)
            gload_lds16(Bt + (size_t)boff[H][i] + (size_t)tt * 64,
                        &Bs[(tt & 1) * 16384 + H * 8192 + (w * 64 + i * 512) * 8]);
    };

    f32x4 acc[8][4];
#pragma unroll
    for (int i = 0; i < 8; i++)
#pragma unroll
        for (int j = 0; j < 4; j++) acc[i][j] = (f32x4){0.f, 0.f, 0.f, 0.f};

    // prologue: A0 both halves, B0 both halves, B1 both halves; keep B1 (4 loads) in flight
    stageA(0, 0); stageA(0, 1);
    stageB(0, 0); stageB(0, 1);
    stageB(1, 0); stageB(1, 1);
    asm volatile("s_waitcnt vmcnt(4)" ::: "memory");
    __builtin_amdgcn_s_barrier();

    bf16x8 bfr[4][2];
    for (int t = 0; t < KT; ++t) {
        const int sl = (t & 1) * 16384;
#pragma unroll
        for (int p = 0; p < 4; ++p) {
            bf16x8 af[2][2];
            if (p == 0) {
#pragma unroll
                for (int fc = 0; fc < 4; fc++)
#pragma unroll
                    for (int kk = 0; kk < 2; kk++)
                        bfr[fc][kk] = *(const bf16x8*)&Bs[sl + (wn * 64 + fc * 16 + lr) * 64 + kk * 32 + lk];
            }
#pragma unroll
            for (int pl = 0; pl < 2; pl++)
#pragma unroll
                for (int kk = 0; kk < 2; kk++)
                    af[pl][kk] = *(const bf16x8*)&As[sl + (wm * 128 + (2 * p + pl) * 16 + lr) * 64 + kk * 32 + lk];
            // stage one half-tile
            if (p == 0 && t + 1 < KT) stageA(t + 1, 0);
            if (p == 1 && t + 1 < KT) stageA(t + 1, 1);
            if (p == 2 && t + 2 < KT) stageB(t + 2, 0);
            if (p == 3 && t + 2 < KT) stageB(t + 2, 1);
            __builtin_amdgcn_s_barrier();
            asm volatile("s_waitcnt lgkmcnt(0)" ::: "memory");
            __builtin_amdgcn_sched_barrier(0);
            __builtin_amdgcn_s_setprio(1);
#pragma unroll
            for (int pl = 0; pl < 2; pl++)
#pragma unroll
                for (int fc = 0; fc < 4; fc++)
#pragma unroll
                    for (int kk = 0; kk < 2; kk++)
                        acc[2 * p + pl][fc] = __builtin_amdgcn_mfma_f32_16x16x32_bf16(
                            af[pl][kk], bfr[fc][kk], acc[2 * p + pl][fc], 0, 0, 0);
            __builtin_amdgcn_s_setprio(0);
            if (p == 3) {
                if (t + 2 < KT) asm volatile("s_waitcnt vmcnt(4)" ::: "memory");
                else            asm volatile("s_waitcnt vmcnt(0)" ::: "memory");
            }
            __builtin_amdgcn_s_barrier();
        }
    }

    const int rg0 = (lane >> 4) * 4;
#pragma unroll
    for (int fr = 0; fr < 8; fr++) {
#pragma unroll
        for (int fc = 0; fc < 4; fc++) {
            int cn = n0 + wn * 64 + fc * 16 + lr;
            float bi = bias[e * N + cn];
            f32x4 v = acc[fr][fc];
#pragma unroll
            for (int rg = 0; rg < 4; rg++) {
                int rm = m0 + wm * 128 + fr * 16 + rg0 + rg;
                if (rm < ne) {
                    if (MODE == 0) {
                        float xv = v[rg] + bi;
                        float g = 0.5f * xv * (1.0f + erff(xv * 0.70710678118654752f));
                        Hout[(size_t)(base + rm) * H_DIM + cn] = f2bf(g);
                    } else {
                        int s = base + rm;
                        int tok = perm[s];
                        float wv = wgt[s];
                        unsafeAtomicAdd(&Out[(size_t)tok * D_DIM + cn], wv * (v[rg] + bi));
                    }
                }
            }
        }
    }
}

// ---------------- launch ----------------

extern "C" void kernel_launch(void* const* d_in, const int* in_sizes, int n_in,
                              void* d_out, int out_size, void* d_ws, size_t ws_size,
                              hipStream_t stream) {
    const float* x  = (const float*)d_in[0];
    const float* Wg = (const float*)d_in[1];
    const float* bg = (const float*)d_in[2];
    const float* W1 = (const float*)d_in[3];
    const float* b1 = (const float*)d_in[4];
    const float* W2 = (const float*)d_in[5];
    const float* b2 = (const float*)d_in[6];
    float* out = (float*)d_out;

    char* p = (char*)d_ws;
    ushort_t* xb  = (ushort_t*)p; p += (size_t)N_TOK * D_DIM * 2;
    ushort_t* W1T = (ushort_t*)p; p += (size_t)E_EXPERTS * H_DIM * D_DIM * 2;
    ushort_t* W2T = (ushort_t*)p; p += (size_t)E_EXPERTS * D_DIM * H_DIM * 2;
    ushort_t* Hb  = (ushort_t*)p; p += (size_t)SLOTS * H_DIM * 2;
    int*   top_idx = (int*)p;   p += (size_t)N_TOK * 2 * 4;
    float* top_w   = (float*)p; p += (size_t)N_TOK * 2 * 4;
    int*   perm    = (int*)p;   p += (size_t)SLOTS * 4;
    float* wgt     = (float*)p; p += (size_t)SLOTS * 4;
    int*   counts  = (int*)p;   p += 64;
    int*   offsets = (int*)p;   p += 64;
    int*   cursors = (int*)p;   p += 64;

    hipMemsetAsync(d_out, 0, (size_t)out_size * sizeof(float), stream);
    hipMemsetAsync(counts, 0, 64, stream);

    gate_kernel<<<N_TOK / 4, 256, 0, stream>>>(x, Wg, bg, xb, top_idx, top_w, counts);
    transpose_conv_kernel<<<dim3(H_DIM / 64, D_DIM / 64, E_EXPERTS), 256, 0, stream>>>(W1, W1T, D_DIM, H_DIM);
    transpose_conv_kernel<<<dim3(D_DIM / 64, H_DIM / 64, E_EXPERTS), 256, 0, stream>>>(W2, W2T, H_DIM, D_DIM);
    scan_kernel<<<1, 64, 0, stream>>>(counts, offsets, cursors);
    scatter_kernel<<<N_TOK / 256, 256, 0, stream>>>(top_idx, top_w, offsets, cursors, perm, wgt);
    moe_gemm_kernel<0><<<dim3(H_DIM / 256, 32, E_EXPERTS), 512, 0, stream>>>(
        xb, W1T, b1, offsets, counts, perm, wgt, Hb, nullptr);
    moe_gemm_kernel<1><<<dim3(D_DIM / 256, 32, E_EXPERTS), 512, 0, stream>>>(
        Hb, W2T, b2, offsets, counts, perm, wgt, nullptr, out);
}

// Round 4
// 654.894 us; speedup vs baseline: 1.1723x; 1.1723x over previous
//
#include <hip/hip_runtime.h>
#include <hip/hip_bf16.h>
#include <math.h>

#define E_EXPERTS 8
#define D_DIM 768
#define H_DIM 3072
#define N_TOK 8192          // B*T = 4*2048
#define SLOTS (2 * N_TOK)

typedef unsigned short ushort_t;
typedef __attribute__((ext_vector_type(8))) __bf16 bf16x8;
typedef __attribute__((ext_vector_type(4))) float f32x4;

__device__ __forceinline__ unsigned short f2bf(float f) {
    unsigned int u = __float_as_uint(f);
    unsigned int r = (u + 0x7FFFu + ((u >> 16) & 1u)) >> 16;
    return (unsigned short)r;
}

// async 16B global -> LDS (wave-uniform LDS base + lane*16; global addr per-lane)
__device__ __forceinline__ void gload_lds16(const void* g, void* l) {
    __builtin_amdgcn_global_load_lds(
        (const __attribute__((address_space(1))) unsigned int*)g,
        (__attribute__((address_space(3))) unsigned int*)l, 16, 0, 0);
}

// ---------------- prep kernels ----------------

// dst[e][c][r] = bf16(src[e][r][c]);  R,C multiples of 64
__global__ void transpose_conv_kernel(const float* __restrict__ src, ushort_t* __restrict__ dst,
                                      int R, int C) {
    __shared__ float tile[64][65];
    int e = blockIdx.z;
    const float* S = src + (size_t)e * R * C;
    ushort_t* Dp = dst + (size_t)e * R * C;
    int c0 = blockIdx.x * 64, r0 = blockIdx.y * 64;
    int tx = threadIdx.x & 15, ty = threadIdx.x >> 4;  // 16 x 16
#pragma unroll
    for (int p = 0; p < 4; p++) {
        float4 v = *(const float4*)&S[(size_t)(r0 + ty + 16 * p) * C + c0 + tx * 4];
        tile[ty + 16 * p][tx * 4 + 0] = v.x;
        tile[ty + 16 * p][tx * 4 + 1] = v.y;
        tile[ty + 16 * p][tx * 4 + 2] = v.z;
        tile[ty + 16 * p][tx * 4 + 3] = v.w;
    }
    __syncthreads();
#pragma unroll
    for (int p = 0; p < 4; p++) {
        int cc = ty + 16 * p;
        int rr = tx * 4;
        ushort4 o;
        o.x = f2bf(tile[rr + 0][cc]);
        o.y = f2bf(tile[rr + 1][cc]);
        o.z = f2bf(tile[rr + 2][cc]);
        o.w = f2bf(tile[rr + 3][cc]);
        *(ushort4*)&Dp[(size_t)(c0 + cc) * R + r0 + rr] = o;
    }
}

// ---------------- routing (fused with x -> bf16 conversion) ----------------

__global__ void gate_kernel(const float* __restrict__ x, const float* __restrict__ Wg,
                            const float* __restrict__ bg, ushort_t* __restrict__ xb,
                            int* __restrict__ top_idx, float* __restrict__ top_w,
                            int* __restrict__ counts) {
    int w = threadIdx.x >> 6, lane = threadIdx.x & 63;
    int t = blockIdx.x * 4 + w;
    if (t >= N_TOK) return;
    const float* xr = x + (size_t)t * D_DIM;
    float xs[12];
#pragma unroll
    for (int j = 0; j < 12; j++) xs[j] = xr[lane + 64 * j];
#pragma unroll
    for (int j = 0; j < 12; j++) xb[(size_t)t * D_DIM + lane + 64 * j] = f2bf(xs[j]);
    float pr[8];
#pragma unroll
    for (int ee = 0; ee < 8; ee++) {
        const float* wr = Wg + ee * D_DIM;
        float p = 0.f;
#pragma unroll
        for (int j = 0; j < 12; j++) p += xs[j] * wr[lane + 64 * j];
#pragma unroll
        for (int o = 32; o > 0; o >>= 1) p += __shfl_xor(p, o);
        pr[ee] = p + bg[ee];
    }
    float mx = pr[0];
#pragma unroll
    for (int ee = 1; ee < 8; ee++) mx = fmaxf(mx, pr[ee]);
    float s = 0.f;
#pragma unroll
    for (int ee = 0; ee < 8; ee++) { pr[ee] = expf(pr[ee] - mx); s += pr[ee]; }
    float inv = 1.f / s;
#pragma unroll
    for (int ee = 0; ee < 8; ee++) pr[ee] *= inv;
    int i0 = 0;
#pragma unroll
    for (int ee = 1; ee < 8; ee++) if (pr[ee] > pr[i0]) i0 = ee;
    int i1 = -1;
#pragma unroll
    for (int ee = 0; ee < 8; ee++) {
        if (ee == i0) continue;
        if (i1 < 0 || pr[ee] > pr[i1]) i1 = ee;
    }
    if (lane == 0) {
        top_idx[2 * t] = i0;
        top_idx[2 * t + 1] = i1;
        top_w[2 * t] = pr[i0];
        top_w[2 * t + 1] = pr[i1];
        atomicAdd(&counts[i0], 1);
        atomicAdd(&counts[i1], 1);
    }
}

__global__ void scan_kernel(const int* __restrict__ counts, int* __restrict__ offsets,
                            int* __restrict__ cursors) {
    if (threadIdx.x == 0) {
        int acc = 0;
        for (int e = 0; e < E_EXPERTS; e++) { offsets[e] = acc; acc += counts[e]; }
    }
    if (threadIdx.x < E_EXPERTS) cursors[threadIdx.x] = 0;
}

__global__ void scatter_kernel(const int* __restrict__ top_idx, const float* __restrict__ top_w,
                               const int* __restrict__ offsets, int* __restrict__ cursors,
                               int* __restrict__ perm, float* __restrict__ wgt) {
    int t = blockIdx.x * blockDim.x + threadIdx.x;
    if (t >= N_TOK) return;
#pragma unroll
    for (int sl = 0; sl < 2; sl++) {
        int ee = top_idx[2 * t + sl];
        int p = atomicAdd(&cursors[ee], 1);
        int s = offsets[ee] + p;
        perm[s] = t;
        wgt[s] = top_w[2 * t + sl];
    }
}

// ---------------- expert GEMMs: 256x256 8-phase (T2+T3+T4+T5) ----------------
// 512 threads = 8 waves (2M x 4N). BM=BN=256, BK=64. LDS: 2 dbuf x [2 half x 128 x 64] bf16, A and B.
// T2 swizzle (both-sides, granule-XOR): LDS dest linear (global_load_lds), global SOURCE fetches
// logical 16B-granule (pg ^ (row&7)); fragment reads XOR granule with (lr&7). 16-way -> 2-way.
// Staging per tile t: p0/p1 -> A_{t+1} h0/h1, p2/p3 -> B_{t+2} h0/h1; boundary wait vmcnt(4).
// MODE 0: A gathered via perm, B = W1T[e], epilogue GELU(tanh-form) -> Hout bf16
// MODE 1: A = Hb contiguous,  B = W2T[e], epilogue weighted atomic -> Out f32
template <int MODE>
__global__ __launch_bounds__(512, 2) void moe_gemm_kernel(
    const ushort_t* __restrict__ A, const ushort_t* __restrict__ BT,
    const float* __restrict__ bias, const int* __restrict__ offsets,
    const int* __restrict__ counts, const int* __restrict__ perm,
    const float* __restrict__ wgt, ushort_t* __restrict__ Hout, float* __restrict__ Out) {
    constexpr int K = (MODE == 0) ? D_DIM : H_DIM;
    constexpr int N = (MODE == 0) ? H_DIM : D_DIM;
    constexpr int KT = K / 64;

    const int e = blockIdx.z;
    const int ne = counts[e];
    const int m0 = blockIdx.y * 256;
    if (m0 >= ne) return;
    const int n0 = blockIdx.x * 256;
    const int base = offsets[e];
    const ushort_t* Bt = BT + (size_t)e * ((size_t)N * K);

    __shared__ alignas(16) ushort_t As[2 * 256 * 64];
    __shared__ alignas(16) ushort_t Bs[2 * 256 * 64];

    const int tid = threadIdx.x;
    const int lane = tid & 63;
    const int w = tid >> 6;
    const int wm = w >> 2, wn = w & 3;           // 2 x 4 wave grid
    const int lr = lane & 15, lk = (lane >> 4) * 8;
    const int gx = lr & 7;                       // read-side granule XOR

    // staging: thread covers physical granule (row = H*128 + (tid>>3) + i*64, pg = tid&7).
    // pre-swizzled SOURCE granule = pg ^ (row&7) = (tid&7) ^ ((tid>>3)&7)  (row&7 == (tid>>3)&7)
    const int r0s = tid >> 3;
    const int c8 = (((tid & 7) ^ ((tid >> 3) & 7)) * 8);
    int aoff[2][2], boff[2][2];                  // [half][i], element offsets
#pragma unroll
    for (int H = 0; H < 2; H++)
#pragma unroll
        for (int i = 0; i < 2; i++) {
            int trow = H * 128 + r0s + i * 64;
            int rcl = min(m0 + trow, ne - 1);
            int arow = (MODE == 0) ? perm[base + rcl] : (base + rcl);
            aoff[H][i] = arow * K + c8;
            boff[H][i] = (n0 + trow) * K + c8;
        }

    auto stageA = [&](int tt, int H) {
#pragma unroll
        for (int i = 0; i < 2; i++)
            gload_lds16(A + (size_t)aoff[H][i] + (size_t)tt * 64,
                        &As[(tt & 1) * 16384 + H * 8192 + (w * 64 + i * 512) * 8]);
    };
    auto stageB = [&](int tt, int H) {
#pragma unroll
        for (int i = 0; i < 2; i++)
            gload_lds16(Bt + (size_t)boff[H][i] + (size_t)tt * 64,
                        &Bs[(tt & 1) * 16384 + H * 8192 + (w * 64 + i * 512) * 8]);
    };

    f32x4 acc[8][4];
#pragma unroll
    for (int i = 0; i < 8; i++)
#pragma unroll
        for (int j = 0; j < 4; j++) acc[i][j] = (f32x4){0.f, 0.f, 0.f, 0.f};

    // prologue: A0, B0, B1; keep B1 (4 loads) in flight
    stageA(0, 0); stageA(0, 1);
    stageB(0, 0); stageB(0, 1);
    stageB(1, 0); stageB(1, 1);
    asm volatile("s_waitcnt vmcnt(4)" ::: "memory");
    __builtin_amdgcn_s_barrier();

    // swizzled read column terms (granule = (kk*4 + lk/8) ^ gx, within-granule offset 0)
    const int colA0 = (((0 * 4) + (lk >> 3)) ^ gx) << 3;
    const int colA1 = (((1 * 4) + (lk >> 3)) ^ gx) << 3;

    bf16x8 bfr[4][2];
    for (int t = 0; t < KT; ++t) {
        const int sl = (t & 1) * 16384;
#pragma unroll
        for (int p = 0; p < 4; ++p) {
            bf16x8 af[2][2];
            if (p == 0) {
#pragma unroll
                for (int fc = 0; fc < 4; fc++) {
                    int row = wn * 64 + fc * 16 + lr;
                    bfr[fc][0] = *(const bf16x8*)&Bs[sl + row * 64 + colA0];
                    bfr[fc][1] = *(const bf16x8*)&Bs[sl + row * 64 + colA1];
                }
            }
#pragma unroll
            for (int pl = 0; pl < 2; pl++) {
                int row = wm * 128 + (2 * p + pl) * 16 + lr;
                af[pl][0] = *(const bf16x8*)&As[sl + row * 64 + colA0];
                af[pl][1] = *(const bf16x8*)&As[sl + row * 64 + colA1];
            }
            // stage one half-tile
            if (p == 0 && t + 1 < KT) stageA(t + 1, 0);
            if (p == 1 && t + 1 < KT) stageA(t + 1, 1);
            if (p == 2 && t + 2 < KT) stageB(t + 2, 0);
            if (p == 3 && t + 2 < KT) stageB(t + 2, 1);
            __builtin_amdgcn_s_barrier();
            asm volatile("s_waitcnt lgkmcnt(0)" ::: "memory");
            __builtin_amdgcn_s_setprio(1);
#pragma unroll
            for (int pl = 0; pl < 2; pl++)
#pragma unroll
                for (int fc = 0; fc < 4; fc++)
#pragma unroll
                    for (int kk = 0; kk < 2; kk++)
                        acc[2 * p + pl][fc] = __builtin_amdgcn_mfma_f32_16x16x32_bf16(
                            af[pl][kk], bfr[fc][kk], acc[2 * p + pl][fc], 0, 0, 0);
            __builtin_amdgcn_s_setprio(0);
            if (p == 3) {
                if (t + 2 < KT) asm volatile("s_waitcnt vmcnt(4)" ::: "memory");
                else            asm volatile("s_waitcnt vmcnt(0)" ::: "memory");
            }
            __builtin_amdgcn_s_barrier();
        }
    }

    const int rg0 = (lane >> 4) * 4;
#pragma unroll
    for (int fr = 0; fr < 8; fr++) {
#pragma unroll
        for (int fc = 0; fc < 4; fc++) {
            int cn = n0 + wn * 64 + fc * 16 + lr;
            float bi = bias[e * N + cn];
            f32x4 v = acc[fr][fc];
#pragma unroll
            for (int rg = 0; rg < 4; rg++) {
                int rm = m0 + wm * 128 + fr * 16 + rg0 + rg;
                if (rm < ne) {
                    if (MODE == 0) {
                        float xv = v[rg] + bi;
                        // gelu(x) ~= x * sigmoid(2*0.7978845608*(x + 0.044715 x^3))
                        float u = xv * 1.5957691216f * __builtin_fmaf(0.044715f * xv, xv, 1.0f);
                        float g = xv / (1.f + __expf(-u));
                        Hout[(size_t)(base + rm) * H_DIM + cn] = f2bf(g);
                    } else {
                        int s = base + rm;
                        int tok = perm[s];
                        float wv = wgt[s];
                        unsafeAtomicAdd(&Out[(size_t)tok * D_DIM + cn], wv * (v[rg] + bi));
                    }
                }
            }
        }
    }
}

// ---------------- launch ----------------

extern "C" void kernel_launch(void* const* d_in, const int* in_sizes, int n_in,
                              void* d_out, int out_size, void* d_ws, size_t ws_size,
                              hipStream_t stream) {
    const float* x  = (const float*)d_in[0];
    const float* Wg = (const float*)d_in[1];
    const float* bg = (const float*)d_in[2];
    const float* W1 = (const float*)d_in[3];
    const float* b1 = (const float*)d_in[4];
    const float* W2 = (const float*)d_in[5];
    const float* b2 = (const float*)d_in[6];
    float* out = (float*)d_out;

    char* p = (char*)d_ws;
    ushort_t* xb  = (ushort_t*)p; p += (size_t)N_TOK * D_DIM * 2;
    ushort_t* W1T = (ushort_t*)p; p += (size_t)E_EXPERTS * H_DIM * D_DIM * 2;
    ushort_t* W2T = (ushort_t*)p; p += (size_t)E_EXPERTS * D_DIM * H_DIM * 2;
    ushort_t* Hb  = (ushort_t*)p; p += (size_t)SLOTS * H_DIM * 2;
    int*   top_idx = (int*)p;   p += (size_t)N_TOK * 2 * 4;
    float* top_w   = (float*)p; p += (size_t)N_TOK * 2 * 4;
    int*   perm    = (int*)p;   p += (size_t)SLOTS * 4;
    float* wgt     = (float*)p; p += (size_t)SLOTS * 4;
    int*   counts  = (int*)p;   p += 64;
    int*   offsets = (int*)p;   p += 64;
    int*   cursors = (int*)p;   p += 64;

    hipMemsetAsync(d_out, 0, (size_t)out_size * sizeof(float), stream);
    hipMemsetAsync(counts, 0, 64, stream);

    gate_kernel<<<N_TOK / 4, 256, 0, stream>>>(x, Wg, bg, xb, top_idx, top_w, counts);
    transpose_conv_kernel<<<dim3(H_DIM / 64, D_DIM / 64, E_EXPERTS), 256, 0, stream>>>(W1, W1T, D_DIM, H_DIM);
    transpose_conv_kernel<<<dim3(D_DIM / 64, H_DIM / 64, E_EXPERTS), 256, 0, stream>>>(W2, W2T, H_DIM, D_DIM);
    scan_kernel<<<1, 64, 0, stream>>>(counts, offsets, cursors);
    scatter_kernel<<<N_TOK / 256, 256, 0, stream>>>(top_idx, top_w, offsets, cursors, perm, wgt);
    moe_gemm_kernel<0><<<dim3(H_DIM / 256, 32, E_EXPERTS), 512, 0, stream>>>(
        xb, W1T, b1, offsets, counts, perm, wgt, Hb, nullptr);
    moe_gemm_kernel<1><<<dim3(D_DIM / 256, 32, E_EXPERTS), 512, 0, stream>>>(
        Hb, W2T, b2, offsets, counts, perm, wgt, nullptr, out);
}

// Round 5
// 411.690 us; speedup vs baseline: 1.8648x; 1.5907x over previous
//
#include <hip/hip_runtime.h>
#include <hip/hip_bf16.h>
#include <math.h>

#define E_EXPERTS 8
#define D_DIM 768
#define H_DIM 3072
#define N_TOK 8192          // B*T = 4*2048
#define SLOTS (2 * N_TOK)
#define SCAT_BLOCKS 32      // hist/scatter blocks (256 tokens each)

typedef unsigned short ushort_t;
typedef __attribute__((ext_vector_type(8))) __bf16 bf16x8;
typedef __attribute__((ext_vector_type(4))) float f32x4;

__device__ __forceinline__ unsigned short f2bf(float f) {
    unsigned int u = __float_as_uint(f);
    unsigned int r = (u + 0x7FFFu + ((u >> 16) & 1u)) >> 16;
    return (unsigned short)r;
}

// async 16B global -> LDS (wave-uniform LDS base + lane*16; global addr per-lane)
__device__ __forceinline__ void gload_lds16(const void* g, void* l) {
    __builtin_amdgcn_global_load_lds(
        (const __attribute__((address_space(1))) unsigned int*)g,
        (__attribute__((address_space(3))) unsigned int*)l, 16, 0, 0);
}

// ---------------- prep kernels ----------------

// dst[e][c][r] = bf16(src[e][r][c]);  R,C multiples of 64
__global__ void transpose_conv_kernel(const float* __restrict__ src, ushort_t* __restrict__ dst,
                                      int R, int C) {
    __shared__ float tile[64][65];
    int e = blockIdx.z;
    const float* S = src + (size_t)e * R * C;
    ushort_t* Dp = dst + (size_t)e * R * C;
    int c0 = blockIdx.x * 64, r0 = blockIdx.y * 64;
    int tx = threadIdx.x & 15, ty = threadIdx.x >> 4;  // 16 x 16
#pragma unroll
    for (int p = 0; p < 4; p++) {
        float4 v = *(const float4*)&S[(size_t)(r0 + ty + 16 * p) * C + c0 + tx * 4];
        tile[ty + 16 * p][tx * 4 + 0] = v.x;
        tile[ty + 16 * p][tx * 4 + 1] = v.y;
        tile[ty + 16 * p][tx * 4 + 2] = v.z;
        tile[ty + 16 * p][tx * 4 + 3] = v.w;
    }
    __syncthreads();
#pragma unroll
    for (int p = 0; p < 4; p++) {
        int cc = ty + 16 * p;
        int rr = tx * 4;
        ushort4 o;
        o.x = f2bf(tile[rr + 0][cc]);
        o.y = f2bf(tile[rr + 1][cc]);
        o.z = f2bf(tile[rr + 2][cc]);
        o.w = f2bf(tile[rr + 3][cc]);
        *(ushort4*)&Dp[(size_t)(c0 + cc) * R + r0 + rr] = o;
    }
}

// ---------------- routing ----------------

__global__ void gate_kernel(const float* __restrict__ x, const float* __restrict__ Wg,
                            const float* __restrict__ bg, ushort_t* __restrict__ xb,
                            int* __restrict__ top_idx, float* __restrict__ top_w) {
    int w = threadIdx.x >> 6, lane = threadIdx.x & 63;
    int t = blockIdx.x * 4 + w;
    if (t >= N_TOK) return;
    const float* xr = x + (size_t)t * D_DIM;
    float xs[12];
#pragma unroll
    for (int j = 0; j < 12; j++) xs[j] = xr[lane + 64 * j];
#pragma unroll
    for (int j = 0; j < 12; j++) xb[(size_t)t * D_DIM + lane + 64 * j] = f2bf(xs[j]);
    float pr[8];
#pragma unroll
    for (int ee = 0; ee < 8; ee++) {
        const float* wr = Wg + ee * D_DIM;
        float p = 0.f;
#pragma unroll
        for (int j = 0; j < 12; j++) p += xs[j] * wr[lane + 64 * j];
#pragma unroll
        for (int o = 32; o > 0; o >>= 1) p += __shfl_xor(p, o);
        pr[ee] = p + bg[ee];
    }
    float mx = pr[0];
#pragma unroll
    for (int ee = 1; ee < 8; ee++) mx = fmaxf(mx, pr[ee]);
    float s = 0.f;
#pragma unroll
    for (int ee = 0; ee < 8; ee++) { pr[ee] = expf(pr[ee] - mx); s += pr[ee]; }
    float inv = 1.f / s;
#pragma unroll
    for (int ee = 0; ee < 8; ee++) pr[ee] *= inv;
    int i0 = 0;
#pragma unroll
    for (int ee = 1; ee < 8; ee++) if (pr[ee] > pr[i0]) i0 = ee;
    int i1 = -1;
#pragma unroll
    for (int ee = 0; ee < 8; ee++) {
        if (ee == i0) continue;
        if (i1 < 0 || pr[ee] > pr[i1]) i1 = ee;
    }
    if (lane == 0) {
        top_idx[2 * t] = i0;
        top_idx[2 * t + 1] = i1;
        top_w[2 * t] = pr[i0];
        top_w[2 * t + 1] = pr[i1];
    }
}

// per-block expert histogram via LDS (8 global atomic-free writes per block)
__global__ void hist_kernel(const int* __restrict__ top_idx, int* __restrict__ bc) {
    __shared__ int h[E_EXPERTS];
    if (threadIdx.x < E_EXPERTS) h[threadIdx.x] = 0;
    __syncthreads();
    int t = blockIdx.x * 256 + threadIdx.x;
    atomicAdd(&h[top_idx[2 * t]], 1);
    atomicAdd(&h[top_idx[2 * t + 1]], 1);
    __syncthreads();
    if (threadIdx.x < E_EXPERTS) bc[blockIdx.x * E_EXPERTS + threadIdx.x] = h[threadIdx.x];
}

// two-level scan: counts[e], offsets[e], base[b][e]
__global__ void scan_kernel(const int* __restrict__ bc, int* __restrict__ counts,
                            int* __restrict__ offsets, int* __restrict__ base) {
    int tid = threadIdx.x;
    if (tid < E_EXPERTS) {
        int acc = 0;
        for (int b = 0; b < SCAT_BLOCKS; b++) {
            base[b * E_EXPERTS + tid] = acc;
            acc += bc[b * E_EXPERTS + tid];
        }
        counts[tid] = acc;
    }
    __syncthreads();
    if (tid == 0) {
        int acc = 0;
        for (int e = 0; e < E_EXPERTS; e++) { offsets[e] = acc; acc += counts[e]; }
    }
    __syncthreads();
    if (tid < E_EXPERTS) {
        int o = offsets[tid];
        for (int b = 0; b < SCAT_BLOCKS; b++) base[b * E_EXPERTS + tid] += o;
    }
}

__global__ void scatter_kernel(const int* __restrict__ top_idx, const float* __restrict__ top_w,
                               const int* __restrict__ base, int* __restrict__ perm,
                               float* __restrict__ wgt) {
    __shared__ int cur[E_EXPERTS];
    if (threadIdx.x < E_EXPERTS) cur[threadIdx.x] = 0;
    __syncthreads();
    int t = blockIdx.x * 256 + threadIdx.x;
#pragma unroll
    for (int sl = 0; sl < 2; sl++) {
        int ee = top_idx[2 * t + sl];
        int p = atomicAdd(&cur[ee], 1);
        int s = base[blockIdx.x * E_EXPERTS + ee] + p;
        perm[s] = t;
        wgt[s] = top_w[2 * t + sl];
    }
}

// ---------------- expert GEMMs: 256x256 8-phase (T1+T2+T3+T4+T5) ----------------
// 1-D XCD-grouped grid: wgid = c + 8*(mb + 32*q); group g=q*8+c -> (e = g/NB, nb = g%NB).
// All 32 mb-blocks of one (e,nb) land consecutively on XCD c -> B panel L2-resident, reused ~8x.
// 512 threads = 8 waves (2M x 4N). BM=BN=256, BK=64. T2 granule-XOR swizzle both-sides.
// Staging per tile t: p0/p1 -> A_{t+1} h0/h1, p2/p3 -> B_{t+2} h0/h1; boundary wait vmcnt(4).
// MODE 0: A gathered via perm, B = W1T[e], epilogue GELU -> Hout bf16
// MODE 1: A = Hb contiguous,  B = W2T[e], epilogue weighted atomic -> Out f32
template <int MODE>
__global__ __launch_bounds__(512, 2) void moe_gemm_kernel(
    const ushort_t* __restrict__ A, const ushort_t* __restrict__ BT,
    const float* __restrict__ bias, const int* __restrict__ offsets,
    const int* __restrict__ counts, const int* __restrict__ perm,
    const float* __restrict__ wgt, ushort_t* __restrict__ Hout, float* __restrict__ Out) {
    constexpr int K = (MODE == 0) ? D_DIM : H_DIM;
    constexpr int N = (MODE == 0) ? H_DIM : D_DIM;
    constexpr int KT = K / 64;
    constexpr int NB = N / 256;

    const int wgid = blockIdx.x;
    const int c = wgid & 7;
    const int r = wgid >> 3;
    const int mb = r & 31;
    const int q = r >> 5;
    const int g = q * 8 + c;
    const int e = g / NB;
    const int nb = g % NB;

    const int ne = counts[e];
    const int m0 = mb * 256;
    if (m0 >= ne) return;
    const int n0 = nb * 256;
    const int base = offsets[e];
    const ushort_t* Bt = BT + (size_t)e * ((size_t)N * K);

    __shared__ alignas(16) ushort_t As[2 * 256 * 64];
    __shared__ alignas(16) ushort_t Bs[2 * 256 * 64];

    const int tid = threadIdx.x;
    const int lane = tid & 63;
    const int w = tid >> 6;
    const int wm = w >> 2, wn = w & 3;           // 2 x 4 wave grid
    const int lr = lane & 15, lk = (lane >> 4) * 8;
    const int gx = lr & 7;                       // read-side granule XOR

    // staging: physical granule (row = H*128 + (tid>>3) + i*64, pg = tid&7);
    // pre-swizzled SOURCE granule = pg ^ (row&7)
    const int r0s = tid >> 3;
    const int c8 = (((tid & 7) ^ ((tid >> 3) & 7)) * 8);
    int aoff[2][2], boff[2][2];                  // [half][i], element offsets
#pragma unroll
    for (int H = 0; H < 2; H++)
#pragma unroll
        for (int i = 0; i < 2; i++) {
            int trow = H * 128 + r0s + i * 64;
            int rcl = min(m0 + trow, ne - 1);
            int arow = (MODE == 0) ? perm[base + rcl] : (base + rcl);
            aoff[H][i] = arow * K + c8;
            boff[H][i] = (n0 + trow) * K + c8;
        }

    auto stageA = [&](int tt, int H) {
#pragma unroll
        for (int i = 0; i < 2; i++)
            gload_lds16(A + (size_t)aoff[H][i] + (size_t)tt * 64,
                        &As[(tt & 1) * 16384 + H * 8192 + (w * 64 + i * 512) * 8]);
    };
    auto stageB = [&](int tt, int H) {
#pragma unroll
        for (int i = 0; i < 2; i++)
            gload_lds16(Bt + (size_t)boff[H][i] + (size_t)tt * 64,
                        &Bs[(tt & 1) * 16384 + H * 8192 + (w * 64 + i * 512) * 8]);
    };

    f32x4 acc[8][4];
#pragma unroll
    for (int i = 0; i < 8; i++)
#pragma unroll
        for (int j = 0; j < 4; j++) acc[i][j] = (f32x4){0.f, 0.f, 0.f, 0.f};

    // prologue: A0, B0, B1; keep B1 (4 loads) in flight
    stageA(0, 0); stageA(0, 1);
    stageB(0, 0); stageB(0, 1);
    stageB(1, 0); stageB(1, 1);
    asm volatile("s_waitcnt vmcnt(4)" ::: "memory");
    __builtin_amdgcn_s_barrier();

    // swizzled read column terms (granule = (kk*4 + lk/8) ^ gx)
    const int colA0 = (((0 * 4) + (lk >> 3)) ^ gx) << 3;
    const int colA1 = (((1 * 4) + (lk >> 3)) ^ gx) << 3;

    bf16x8 bfr[4][2];
    for (int t = 0; t < KT; ++t) {
        const int sl = (t & 1) * 16384;
#pragma unroll
        for (int p = 0; p < 4; ++p) {
            bf16x8 af[2][2];
            if (p == 0) {
#pragma unroll
                for (int fc = 0; fc < 4; fc++) {
                    int row = wn * 64 + fc * 16 + lr;
                    bfr[fc][0] = *(const bf16x8*)&Bs[sl + row * 64 + colA0];
                    bfr[fc][1] = *(const bf16x8*)&Bs[sl + row * 64 + colA1];
                }
            }
#pragma unroll
            for (int pl = 0; pl < 2; pl++) {
                int row = wm * 128 + (2 * p + pl) * 16 + lr;
                af[pl][0] = *(const bf16x8*)&As[sl + row * 64 + colA0];
                af[pl][1] = *(const bf16x8*)&As[sl + row * 64 + colA1];
            }
            // stage one half-tile
            if (p == 0 && t + 1 < KT) stageA(t + 1, 0);
            if (p == 1 && t + 1 < KT) stageA(t + 1, 1);
            if (p == 2 && t + 2 < KT) stageB(t + 2, 0);
            if (p == 3 && t + 2 < KT) stageB(t + 2, 1);
            __builtin_amdgcn_s_barrier();
            asm volatile("s_waitcnt lgkmcnt(0)" ::: "memory");
            __builtin_amdgcn_s_setprio(1);
#pragma unroll
            for (int pl = 0; pl < 2; pl++)
#pragma unroll
                for (int fc = 0; fc < 4; fc++)
#pragma unroll
                    for (int kk = 0; kk < 2; kk++)
                        acc[2 * p + pl][fc] = __builtin_amdgcn_mfma_f32_16x16x32_bf16(
                            af[pl][kk], bfr[fc][kk], acc[2 * p + pl][fc], 0, 0, 0);
            __builtin_amdgcn_s_setprio(0);
            if (p == 3) {
                if (t + 2 < KT) asm volatile("s_waitcnt vmcnt(4)" ::: "memory");
                else            asm volatile("s_waitcnt vmcnt(0)" ::: "memory");
            }
            __builtin_amdgcn_s_barrier();
        }
    }

    const int rg0 = (lane >> 4) * 4;
#pragma unroll
    for (int fr = 0; fr < 8; fr++) {
#pragma unroll
        for (int fc = 0; fc < 4; fc++) {
            int cn = n0 + wn * 64 + fc * 16 + lr;
            float bi = bias[e * N + cn];
            f32x4 v = acc[fr][fc];
#pragma unroll
            for (int rg = 0; rg < 4; rg++) {
                int rm = m0 + wm * 128 + fr * 16 + rg0 + rg;
                if (rm < ne) {
                    if (MODE == 0) {
                        float xv = v[rg] + bi;
                        // gelu(x) ~= x * sigmoid(2*0.7978845608*(x + 0.044715 x^3))
                        float u = xv * 1.5957691216f * __builtin_fmaf(0.044715f * xv, xv, 1.0f);
                        float gl = xv / (1.f + __expf(-u));
                        Hout[(size_t)(base + rm) * H_DIM + cn] = f2bf(gl);
                    } else {
                        int s = base + rm;
                        int tok = perm[s];
                        float wv = wgt[s];
                        unsafeAtomicAdd(&Out[(size_t)tok * D_DIM + cn], wv * (v[rg] + bi));
                    }
                }
            }
        }
    }
}

// ---------------- launch ----------------

extern "C" void kernel_launch(void* const* d_in, const int* in_sizes, int n_in,
                              void* d_out, int out_size, void* d_ws, size_t ws_size,
                              hipStream_t stream) {
    const float* x  = (const float*)d_in[0];
    const float* Wg = (const float*)d_in[1];
    const float* bg = (const float*)d_in[2];
    const float* W1 = (const float*)d_in[3];
    const float* b1 = (const float*)d_in[4];
    const float* W2 = (const float*)d_in[5];
    const float* b2 = (const float*)d_in[6];
    float* out = (float*)d_out;

    char* p = (char*)d_ws;
    ushort_t* xb  = (ushort_t*)p; p += (size_t)N_TOK * D_DIM * 2;
    ushort_t* W1T = (ushort_t*)p; p += (size_t)E_EXPERTS * H_DIM * D_DIM * 2;
    ushort_t* W2T = (ushort_t*)p; p += (size_t)E_EXPERTS * D_DIM * H_DIM * 2;
    ushort_t* Hb  = (ushort_t*)p; p += (size_t)SLOTS * H_DIM * 2;
    int*   top_idx = (int*)p;   p += (size_t)N_TOK * 2 * 4;
    float* top_w   = (float*)p; p += (size_t)N_TOK * 2 * 4;
    int*   perm    = (int*)p;   p += (size_t)SLOTS * 4;
    float* wgt     = (float*)p; p += (size_t)SLOTS * 4;
    int*   bc      = (int*)p;   p += SCAT_BLOCKS * E_EXPERTS * 4;
    int*   basep   = (int*)p;   p += SCAT_BLOCKS * E_EXPERTS * 4;
    int*   counts  = (int*)p;   p += 64;
    int*   offsets = (int*)p;   p += 64;

    hipMemsetAsync(d_out, 0, (size_t)out_size * sizeof(float), stream);

    gate_kernel<<<N_TOK / 4, 256, 0, stream>>>(x, Wg, bg, xb, top_idx, top_w);
    transpose_conv_kernel<<<dim3(H_DIM / 64, D_DIM / 64, E_EXPERTS), 256, 0, stream>>>(W1, W1T, D_DIM, H_DIM);
    transpose_conv_kernel<<<dim3(D_DIM / 64, H_DIM / 64, E_EXPERTS), 256, 0, stream>>>(W2, W2T, H_DIM, D_DIM);
    hist_kernel<<<SCAT_BLOCKS, 256, 0, stream>>>(top_idx, bc);
    scan_kernel<<<1, 64, 0, stream>>>(bc, counts, offsets, basep);
    scatter_kernel<<<SCAT_BLOCKS, 256, 0, stream>>>(top_idx, top_w, basep, perm, wgt);
    moe_gemm_kernel<0><<<8 * 32 * (H_DIM / 256), 512, 0, stream>>>(
        xb, W1T, b1, offsets, counts, perm, wgt, Hb, nullptr);
    moe_gemm_kernel<1><<<8 * 32 * (D_DIM / 256), 512, 0, stream>>>(
        Hb, W2T, b2, offsets, counts, perm, wgt, nullptr, out);
}

// Round 6
// 353.863 us; speedup vs baseline: 2.1695x; 1.1634x over previous
//
#include <hip/hip_runtime.h>
#include <hip/hip_bf16.h>
#include <math.h>

#define E_EXPERTS 8
#define D_DIM 768
#define H_DIM 3072
#define N_TOK 8192          // B*T = 4*2048
#define SLOTS (2 * N_TOK)
#define SCAT_BLOCKS 32      // hist/scatter blocks (256 tokens each)
#define MB_L 20             // launched m-blocks per group (covers ne <= 2560)

typedef unsigned short ushort_t;
typedef __attribute__((ext_vector_type(8))) __bf16 bf16x8;
typedef __attribute__((ext_vector_type(4))) float f32x4;

__device__ __forceinline__ unsigned short f2bf(float f) {
    unsigned int u = __float_as_uint(f);
    unsigned int r = (u + 0x7FFFu + ((u >> 16) & 1u)) >> 16;
    return (unsigned short)r;
}

// async 16B global -> LDS (wave-uniform LDS base + lane*16; global addr per-lane)
__device__ __forceinline__ void gload_lds16(const void* g, void* l) {
    __builtin_amdgcn_global_load_lds(
        (const __attribute__((address_space(1))) unsigned int*)g,
        (__attribute__((address_space(3))) unsigned int*)l, 16, 0, 0);
}

// ---------------- prep kernels ----------------

// dst[e][c][r] = bf16(src[e][r][c]);  R,C multiples of 64
__global__ void transpose_conv_kernel(const float* __restrict__ src, ushort_t* __restrict__ dst,
                                      int R, int C) {
    __shared__ float tile[64][65];
    int e = blockIdx.z;
    const float* S = src + (size_t)e * R * C;
    ushort_t* Dp = dst + (size_t)e * R * C;
    int c0 = blockIdx.x * 64, r0 = blockIdx.y * 64;
    int tx = threadIdx.x & 15, ty = threadIdx.x >> 4;  // 16 x 16
#pragma unroll
    for (int p = 0; p < 4; p++) {
        float4 v = *(const float4*)&S[(size_t)(r0 + ty + 16 * p) * C + c0 + tx * 4];
        tile[ty + 16 * p][tx * 4 + 0] = v.x;
        tile[ty + 16 * p][tx * 4 + 1] = v.y;
        tile[ty + 16 * p][tx * 4 + 2] = v.z;
        tile[ty + 16 * p][tx * 4 + 3] = v.w;
    }
    __syncthreads();
#pragma unroll
    for (int p = 0; p < 4; p++) {
        int cc = ty + 16 * p;
        int rr = tx * 4;
        ushort4 o;
        o.x = f2bf(tile[rr + 0][cc]);
        o.y = f2bf(tile[rr + 1][cc]);
        o.z = f2bf(tile[rr + 2][cc]);
        o.w = f2bf(tile[rr + 3][cc]);
        *(ushort4*)&Dp[(size_t)(c0 + cc) * R + r0 + rr] = o;
    }
}

// ---------------- routing ----------------

__global__ void gate_kernel(const float* __restrict__ x, const float* __restrict__ Wg,
                            const float* __restrict__ bg, ushort_t* __restrict__ xb,
                            int* __restrict__ top_idx, float* __restrict__ top_w) {
    int w = threadIdx.x >> 6, lane = threadIdx.x & 63;
    int t = blockIdx.x * 4 + w;
    if (t >= N_TOK) return;
    const float* xr = x + (size_t)t * D_DIM;
    float xs[12];
#pragma unroll
    for (int j = 0; j < 12; j++) xs[j] = xr[lane + 64 * j];
#pragma unroll
    for (int j = 0; j < 12; j++) xb[(size_t)t * D_DIM + lane + 64 * j] = f2bf(xs[j]);
    float pr[8];
#pragma unroll
    for (int ee = 0; ee < 8; ee++) {
        const float* wr = Wg + ee * D_DIM;
        float p = 0.f;
#pragma unroll
        for (int j = 0; j < 12; j++) p += xs[j] * wr[lane + 64 * j];
#pragma unroll
        for (int o = 32; o > 0; o >>= 1) p += __shfl_xor(p, o);
        pr[ee] = p + bg[ee];
    }
    float mx = pr[0];
#pragma unroll
    for (int ee = 1; ee < 8; ee++) mx = fmaxf(mx, pr[ee]);
    float s = 0.f;
#pragma unroll
    for (int ee = 0; ee < 8; ee++) { pr[ee] = expf(pr[ee] - mx); s += pr[ee]; }
    float inv = 1.f / s;
#pragma unroll
    for (int ee = 0; ee < 8; ee++) pr[ee] *= inv;
    int i0 = 0;
#pragma unroll
    for (int ee = 1; ee < 8; ee++) if (pr[ee] > pr[i0]) i0 = ee;
    int i1 = -1;
#pragma unroll
    for (int ee = 0; ee < 8; ee++) {
        if (ee == i0) continue;
        if (i1 < 0 || pr[ee] > pr[i1]) i1 = ee;
    }
    if (lane == 0) {
        top_idx[2 * t] = i0;
        top_idx[2 * t + 1] = i1;
        top_w[2 * t] = pr[i0];
        top_w[2 * t + 1] = pr[i1];
    }
}

__global__ void hist_kernel(const int* __restrict__ top_idx, int* __restrict__ bc) {
    __shared__ int h[E_EXPERTS];
    if (threadIdx.x < E_EXPERTS) h[threadIdx.x] = 0;
    __syncthreads();
    int t = blockIdx.x * 256 + threadIdx.x;
    atomicAdd(&h[top_idx[2 * t]], 1);
    atomicAdd(&h[top_idx[2 * t + 1]], 1);
    __syncthreads();
    if (threadIdx.x < E_EXPERTS) bc[blockIdx.x * E_EXPERTS + threadIdx.x] = h[threadIdx.x];
}

__global__ void scan_kernel(const int* __restrict__ bc, int* __restrict__ counts,
                            int* __restrict__ offsets, int* __restrict__ base) {
    int tid = threadIdx.x;
    if (tid < E_EXPERTS) {
        int acc = 0;
        for (int b = 0; b < SCAT_BLOCKS; b++) {
            base[b * E_EXPERTS + tid] = acc;
            acc += bc[b * E_EXPERTS + tid];
        }
        counts[tid] = acc;
    }
    __syncthreads();
    if (tid == 0) {
        int acc = 0;
        for (int e = 0; e < E_EXPERTS; e++) { offsets[e] = acc; acc += counts[e]; }
    }
    __syncthreads();
    if (tid < E_EXPERTS) {
        int o = offsets[tid];
        for (int b = 0; b < SCAT_BLOCKS; b++) base[b * E_EXPERTS + tid] += o;
    }
}

__global__ void scatter_kernel(const int* __restrict__ top_idx, const float* __restrict__ top_w,
                               const int* __restrict__ base, int* __restrict__ perm,
                               float* __restrict__ wgt, int* __restrict__ tok2slot) {
    __shared__ int cur[E_EXPERTS];
    if (threadIdx.x < E_EXPERTS) cur[threadIdx.x] = 0;
    __syncthreads();
    int t = blockIdx.x * 256 + threadIdx.x;
#pragma unroll
    for (int sl = 0; sl < 2; sl++) {
        int ee = top_idx[2 * t + sl];
        int p = atomicAdd(&cur[ee], 1);
        int s = base[blockIdx.x * E_EXPERTS + ee] + p;
        perm[s] = t;
        wgt[s] = top_w[2 * t + sl];
        tok2slot[2 * t + sl] = s;
    }
}

// combine: out[t][d] = y[s0][d] + y[s1][d]
__global__ void combine_kernel(const float* __restrict__ y, const int* __restrict__ tok2slot,
                               float* __restrict__ out) {
    int idx = blockIdx.x * blockDim.x + threadIdx.x;
    int stride = gridDim.x * blockDim.x;
    const int QR = D_DIM / 4;  // float4 per row
    for (int i = idx; i < N_TOK * QR; i += stride) {
        int t = i / QR, d4 = i - t * QR;
        int s0 = tok2slot[2 * t], s1 = tok2slot[2 * t + 1];
        float4 a = ((const float4*)(y + (size_t)s0 * D_DIM))[d4];
        float4 b = ((const float4*)(y + (size_t)s1 * D_DIM))[d4];
        float4 o;
        o.x = a.x + b.x; o.y = a.y + b.y; o.z = a.z + b.z; o.w = a.w + b.w;
        ((float4*)(out + (size_t)t * D_DIM))[d4] = o;
    }
}

// ---------------- expert GEMMs: 128x128, BK=64, dbuf, 2 phases/K-tile (T2+T4+T5) ----------------
// 256 threads = 4 waves (2M x 2N); 64 KiB LDS -> 2 blocks/CU (independent barrier domains, m114).
// LDS per operand: 2 buf x [2 half x 64 x 64] bf16 (row-major per half). T2 granule-XOR swizzle
// both-sides: source fetches granule (pg ^ (row&7)); reads XOR granule with (lr&7).
// Tile t: p0 {read B all + A fr0-1; stage A_{t+1} h0+h1} p1 {read A fr2-3; stage B_{t+2} h0+h1}
// boundary vmcnt(4) (keeps B_{t+2} in flight), vmcnt(0) only at tail.
// 1-D XCD-grouped grid: wgid = c + 8*(mb + MB_L*q); g = q*8+c -> (e = g/NB, nb = g%NB).
// MODE 0: A = xb gathered via perm, B = W1T[e], epilogue GELU -> Hout bf16
// MODE 1: A = Hb contiguous,  B = W2T[e], epilogue weighted+bias -> Y f32 (no atomics)
template <int MODE>
__global__ __launch_bounds__(256, 2) void moe_gemm_kernel(
    const ushort_t* __restrict__ A, const ushort_t* __restrict__ BT,
    const float* __restrict__ bias, const int* __restrict__ offsets,
    const int* __restrict__ counts, const int* __restrict__ perm,
    const float* __restrict__ wgt, ushort_t* __restrict__ Hout, float* __restrict__ Y) {
    constexpr int K = (MODE == 0) ? D_DIM : H_DIM;
    constexpr int N = (MODE == 0) ? H_DIM : D_DIM;
    constexpr int KT = K / 64;
    constexpr int NB = N / 128;

    const int wgid = blockIdx.x;
    const int c = wgid & 7;
    const int r = wgid >> 3;
    const int mb = r % MB_L;
    const int q = r / MB_L;
    const int g = q * 8 + c;
    const int e = g / NB;
    const int nb = g % NB;

    const int ne = counts[e];
    const int m0 = mb * 128;
    if (m0 >= ne) return;
    const int n0 = nb * 128;
    const int base = offsets[e];
    const ushort_t* Bt = BT + (size_t)e * ((size_t)N * K);

    __shared__ alignas(16) ushort_t As[2 * 128 * 64];
    __shared__ alignas(16) ushort_t Bs[2 * 128 * 64];

    const int tid = threadIdx.x;
    const int lane = tid & 63;
    const int w = tid >> 6;
    const int wm = w >> 1, wn = w & 1;           // 2 x 2 wave grid
    const int lr = lane & 15, lk = (lane >> 4) * 8;
    const int gx = lr & 7;                       // read-side granule XOR

    // staging: per half (64 rows x 64 cols): granule id = tid + i*256; row = (tid>>3)+i*32, pg = tid&7
    // pre-swizzled SOURCE granule = pg ^ (row&7) = (tid&7) ^ ((tid>>3)&7)
    const int r0s = tid >> 3;
    const int c8 = (((tid & 7) ^ ((tid >> 3) & 7)) * 8);
    int aoff[2][2], boff[2][2];                  // [half][i], element offsets
#pragma unroll
    for (int H = 0; H < 2; H++)
#pragma unroll
        for (int i = 0; i < 2; i++) {
            int trow = H * 64 + r0s + i * 32;
            int rcl = min(m0 + trow, ne - 1);
            int arow = (MODE == 0) ? perm[base + rcl] : (base + rcl);
            aoff[H][i] = arow * K + c8;
            boff[H][i] = (n0 + trow) * K + c8;
        }

    // dest element offset within a half = granule*8; granule = w*64 + i*256 (+lane, HW)
    auto stageA = [&](int tt, int H) {
#pragma unroll
        for (int i = 0; i < 2; i++)
            gload_lds16(A + (size_t)aoff[H][i] + (size_t)tt * 64,
                        &As[(tt & 1) * 8192 + H * 4096 + (w * 64 + i * 256) * 8]);
    };
    auto stageB = [&](int tt, int H) {
#pragma unroll
        for (int i = 0; i < 2; i++)
            gload_lds16(Bt + (size_t)boff[H][i] + (size_t)tt * 64,
                        &Bs[(tt & 1) * 8192 + H * 4096 + (w * 64 + i * 256) * 8]);
    };

    f32x4 acc[4][4];
#pragma unroll
    for (int i = 0; i < 4; i++)
#pragma unroll
        for (int j = 0; j < 4; j++) acc[i][j] = (f32x4){0.f, 0.f, 0.f, 0.f};

    // prologue: A0, B0, B1; keep B1 (4 loads) in flight
    stageA(0, 0); stageA(0, 1);
    stageB(0, 0); stageB(0, 1);
    stageB(1, 0); stageB(1, 1);
    asm volatile("s_waitcnt vmcnt(4)" ::: "memory");
    __builtin_amdgcn_s_barrier();

    // swizzled read columns: granule = (kk*4 + lk/8) ^ gx
    const int colK0 = (((0 * 4) + (lk >> 3)) ^ gx) << 3;
    const int colK1 = (((1 * 4) + (lk >> 3)) ^ gx) << 3;

    bf16x8 bfr[4][2];
    for (int t = 0; t < KT; ++t) {
        const int sl = (t & 1) * 8192;
#pragma unroll
        for (int p = 0; p < 2; ++p) {
            bf16x8 af[2][2];
            if (p == 0) {
#pragma unroll
                for (int fc = 0; fc < 4; fc++) {
                    int R = wn * 64 + fc * 16 + lr;       // 0..127
                    int roff = sl + (R >> 6) * 4096 + (R & 63) * 64;
                    bfr[fc][0] = *(const bf16x8*)&Bs[roff + colK0];
                    bfr[fc][1] = *(const bf16x8*)&Bs[roff + colK1];
                }
            }
#pragma unroll
            for (int pl = 0; pl < 2; pl++) {
                int R = wm * 64 + (2 * p + pl) * 16 + lr;
                int roff = sl + (R >> 6) * 4096 + (R & 63) * 64;
                af[pl][0] = *(const bf16x8*)&As[roff + colK0];
                af[pl][1] = *(const bf16x8*)&As[roff + colK1];
            }
            if (p == 0 && t + 1 < KT) { stageA(t + 1, 0); stageA(t + 1, 1); }
            if (p == 1 && t + 2 < KT) { stageB(t + 2, 0); stageB(t + 2, 1); }
            __builtin_amdgcn_s_barrier();
            asm volatile("s_waitcnt lgkmcnt(0)" ::: "memory");
            __builtin_amdgcn_s_setprio(1);
#pragma unroll
            for (int pl = 0; pl < 2; pl++)
#pragma unroll
                for (int fc = 0; fc < 4; fc++)
#pragma unroll
                    for (int kk = 0; kk < 2; kk++)
                        acc[2 * p + pl][fc] = __builtin_amdgcn_mfma_f32_16x16x32_bf16(
                            af[pl][kk], bfr[fc][kk], acc[2 * p + pl][fc], 0, 0, 0);
            __builtin_amdgcn_s_setprio(0);
            if (p == 1) {
                if (t + 2 < KT) asm volatile("s_waitcnt vmcnt(4)" ::: "memory");
                else            asm volatile("s_waitcnt vmcnt(0)" ::: "memory");
            }
            __builtin_amdgcn_s_barrier();
        }
    }

    const int rg0 = (lane >> 4) * 4;
#pragma unroll
    for (int fr = 0; fr < 4; fr++) {
#pragma unroll
        for (int fc = 0; fc < 4; fc++) {
            int cn = n0 + wn * 64 + fc * 16 + lr;
            float bi = bias[e * N + cn];
            f32x4 v = acc[fr][fc];
#pragma unroll
            for (int rg = 0; rg < 4; rg++) {
                int rm = m0 + wm * 64 + fr * 16 + rg0 + rg;
                if (rm < ne) {
                    if (MODE == 0) {
                        float xv = v[rg] + bi;
                        // gelu(x) ~= x * sigmoid(2*0.7978845608*(x + 0.044715 x^3))
                        float u = xv * 1.5957691216f * __builtin_fmaf(0.044715f * xv, xv, 1.0f);
                        float gl = xv / (1.f + __expf(-u));
                        Hout[(size_t)(base + rm) * H_DIM + cn] = f2bf(gl);
                    } else {
                        int s = base + rm;
                        float wv = wgt[s];
                        Y[(size_t)s * D_DIM + cn] = wv * (v[rg] + bi);
                    }
                }
            }
        }
    }
}

// ---------------- launch ----------------

extern "C" void kernel_launch(void* const* d_in, const int* in_sizes, int n_in,
                              void* d_out, int out_size, void* d_ws, size_t ws_size,
                              hipStream_t stream) {
    const float* x  = (const float*)d_in[0];
    const float* Wg = (const float*)d_in[1];
    const float* bg = (const float*)d_in[2];
    const float* W1 = (const float*)d_in[3];
    const float* b1 = (const float*)d_in[4];
    const float* W2 = (const float*)d_in[5];
    const float* b2 = (const float*)d_in[6];
    float* out = (float*)d_out;

    char* p = (char*)d_ws;
    ushort_t* xb  = (ushort_t*)p; p += (size_t)N_TOK * D_DIM * 2;
    ushort_t* W1T = (ushort_t*)p; p += (size_t)E_EXPERTS * H_DIM * D_DIM * 2;
    ushort_t* W2T = (ushort_t*)p; p += (size_t)E_EXPERTS * D_DIM * H_DIM * 2;
    ushort_t* Hb  = (ushort_t*)p; p += (size_t)SLOTS * H_DIM * 2;
    int*   top_idx = (int*)p;   p += (size_t)N_TOK * 2 * 4;
    float* top_w   = (float*)p; p += (size_t)N_TOK * 2 * 4;
    int*   perm    = (int*)p;   p += (size_t)SLOTS * 4;
    float* wgt     = (float*)p; p += (size_t)SLOTS * 4;
    int*   t2s     = (int*)p;   p += (size_t)SLOTS * 4;
    int*   bc      = (int*)p;   p += SCAT_BLOCKS * E_EXPERTS * 4;
    int*   basep   = (int*)p;   p += SCAT_BLOCKS * E_EXPERTS * 4;
    int*   counts  = (int*)p;   p += 64;
    int*   offsets = (int*)p;   p += 64;
    // y aliases xb+W1T (dead by GEMM2): 50.3 MB < 62.9 MB
    float* y = (float*)d_ws;

    gate_kernel<<<N_TOK / 4, 256, 0, stream>>>(x, Wg, bg, xb, top_idx, top_w);
    transpose_conv_kernel<<<dim3(H_DIM / 64, D_DIM / 64, E_EXPERTS), 256, 0, stream>>>(W1, W1T, D_DIM, H_DIM);
    transpose_conv_kernel<<<dim3(D_DIM / 64, H_DIM / 64, E_EXPERTS), 256, 0, stream>>>(W2, W2T, H_DIM, D_DIM);
    hist_kernel<<<SCAT_BLOCKS, 256, 0, stream>>>(top_idx, bc);
    scan_kernel<<<1, 64, 0, stream>>>(bc, counts, offsets, basep);
    scatter_kernel<<<SCAT_BLOCKS, 256, 0, stream>>>(top_idx, top_w, basep, perm, wgt, t2s);
    moe_gemm_kernel<0><<<8 * MB_L * (H_DIM / 128), 256, 0, stream>>>(
        xb, W1T, b1, offsets, counts, perm, wgt, Hb, nullptr);
    moe_gemm_kernel<1><<<8 * MB_L * (D_DIM / 128), 256, 0, stream>>>(
        Hb, W2T, b2, offsets, counts, perm, wgt, nullptr, y);
    combine_kernel<<<2048, 256, 0, stream>>>(y, t2s, out);
}